// Round 3
// baseline (176.180 us; speedup 1.0000x reference)
//
#include <hip/hip_runtime.h>

#define N_ROWS 32768
#define DIM    256
#define KCODES 2048

typedef unsigned short ushort_t;
typedef __attribute__((ext_vector_type(8)))  short bf16x8;
typedef __attribute__((ext_vector_type(16))) float f32x16;

__device__ __forceinline__ unsigned short f2bf(float f) {
    union { float f; unsigned int u; } v; v.f = f;
    unsigned int r = v.u + 0x7FFFu + ((v.u >> 16) & 1u);   // RNE (inputs finite)
    return (unsigned short)(r >> 16);
}

__device__ __forceinline__ void gl16(const void* g, void* l) {
    __builtin_amdgcn_global_load_lds(
        (const __attribute__((address_space(1))) unsigned int*)g,
        (__attribute__((address_space(3))) unsigned int*)l, 16, 0, 0);
}

// ---------------- prologue: cb -> bf16, halfcn = 0.5*||c||^2, zero loss ---------
__global__ void prep_cb(const float* __restrict__ cb, ushort_t* __restrict__ cbb,
                        float* __restrict__ halfcn, float* __restrict__ loss) {
    const int code = blockIdx.x;
    const int t = threadIdx.x;               // 256 threads = D
    if (code == 0 && t == 0) *loss = 0.0f;
    float v = cb[code * DIM + t];
    cbb[code * DIM + t] = f2bf(v);
    float s = v * v;
    #pragma unroll
    for (int o = 32; o > 0; o >>= 1) s += __shfl_down(s, o, 64);
    __shared__ float red[4];
    if ((t & 63) == 0) red[t >> 6] = s;
    __syncthreads();
    if (t == 0) halfcn[code] = 0.5f * (red[0] + red[1] + red[2] + red[3]);
}

// ---------------- main: 64 rows x 512 codes per block, partial argmax -----------
// score(n,k) = x_n . c_k - 0.5*||c_k||^2  (argmax score == argmin dist)
// A (x rows, bf16) persistent in LDS, staged once with on-the-fly conversion.
// B (codebook) double-buffered via global_load_lds. Partial packed (score|code)
// per row written to part[row*4 + blockIdx.y].
__global__ __launch_bounds__(256, 2) void argmin_mfma(
        const float* __restrict__ x, const ushort_t* __restrict__ cbb,
        const float* __restrict__ halfcn, float* __restrict__ part) {
    __shared__ char As[8][4096];     // [k-chunk][64 rows x 32k bf16], XOR-swizzled 16B pieces
    __shared__ char Bs[2][16384];    // 256 codes x 32k bf16, swizzled
    __shared__ float red[64][4];

    const int t    = threadIdx.x;
    const int lane = t & 63;
    const int w    = t >> 6;         // wave 0..3 -> code quadrant within 256-tile
    const int l32  = lane & 31;
    const int h    = lane >> 5;
    const int row0 = blockIdx.x * 64;
    const int cg0  = blockIdx.y * 512;        // this block's code range base

    // ---- stage A once: fp32 x -> bf16 LDS, swizzled ----
    {
        const int r = t >> 2;                 // 0..63
        const int p = t & 3;                  // source piece 0..3 within 32k chunk
        const int sp = p ^ ((r >> 1) & 3);    // swizzled store position
        #pragma unroll
        for (int kin = 0; kin < 8; kin++) {
            const float* src = x + (size_t)(row0 + r) * DIM + kin * 32 + p * 8;
            float4 v0 = *(const float4*)src;
            float4 v1 = *(const float4*)(src + 4);
            uint4 o;
            o.x = (unsigned)f2bf(v0.x) | ((unsigned)f2bf(v0.y) << 16);
            o.y = (unsigned)f2bf(v0.z) | ((unsigned)f2bf(v0.w) << 16);
            o.z = (unsigned)f2bf(v1.x) | ((unsigned)f2bf(v1.y) << 16);
            o.w = (unsigned)f2bf(v1.z) | ((unsigned)f2bf(v1.w) << 16);
            *(uint4*)(As[kin] + r * 64 + sp * 16) = o;
        }
    }

    // ---- B staging source addresses (16B per lane, swizzled k-piece) ----
    int b_j[4];
    const ushort_t* b_src[4];
    #pragma unroll
    for (int m = 0; m < 4; m++) {
        const int c = (m * 4 + w) * 16 + (lane >> 2);     // local code 0..255
        b_j[m] = (lane & 3) ^ ((c >> 1) & 3);
        b_src[m] = cbb + (size_t)(cg0 + c) * DIM + b_j[m] * 8;
    }

    // ---- preload bias 0.5||c||^2 for this wave's codes (2 code-tiles) ----
    float hcv[2][2];
    #pragma unroll
    for (int tile = 0; tile < 2; tile++)
        #pragma unroll
        for (int ct = 0; ct < 2; ct++)
            hcv[tile][ct] = halfcn[cg0 + tile * 256 + w * 64 + ct * 32 + l32];

    f32x16 acc[2][2];
    #pragma unroll
    for (int rt = 0; rt < 2; rt++)
        #pragma unroll
        for (int ct = 0; ct < 2; ct++)
            #pragma unroll
            for (int r = 0; r < 16; r++) acc[rt][ct][r] = -hcv[0][ct];

    float mp[2][16];
    #pragma unroll
    for (int rt = 0; rt < 2; rt++)
        #pragma unroll
        for (int r = 0; r < 16; r++) mp[rt][r] = -3.0e38f;

    const int fa  = (l32 >> 1) & 3;
    const int pk0 = ((0 + h) ^ fa) * 16;                  // kstep 0 piece offset
    const int pk1 = ((2 + h) ^ fa) * 16;                  // kstep 1 piece offset

    // ---- stage B chunk 0 into buffer 0 ----
    #pragma unroll
    for (int m = 0; m < 4; m++) gl16(b_src[m], Bs[0] + (m * 4 + w) * 1024);

    int cur = 0;
    for (int c = 0; c < 16; ++c) {
        __syncthreads();   // drains vmcnt/lgkm: Bs[cur] staged, A ready, prior reads done
        const int ct8 = c >> 3;
        const int ki  = c & 7;
        if (c < 15) {
            const int cn = c + 1, ctn = cn >> 3, kin = cn & 7;
            const size_t goff = (size_t)ctn * (256 * DIM) + kin * 32;
            #pragma unroll
            for (int m = 0; m < 4; m++)
                gl16(b_src[m] + goff, Bs[cur ^ 1] + (m * 4 + w) * 1024);
        }

        // ---- LDS -> fragments ----
        const char* ab = As[ki];
        const char* bb = Bs[cur];
        bf16x8 af[2][2], bfr[2][2];
        #pragma unroll
        for (int rt = 0; rt < 2; rt++) {
            af[rt][0] = *(const bf16x8*)(ab + (rt * 32 + l32) * 64 + pk0);
            af[rt][1] = *(const bf16x8*)(ab + (rt * 32 + l32) * 64 + pk1);
        }
        #pragma unroll
        for (int ct = 0; ct < 2; ct++) {
            const int cl = w * 64 + ct * 32 + l32;
            bfr[ct][0] = *(const bf16x8*)(bb + cl * 64 + pk0);
            bfr[ct][1] = *(const bf16x8*)(bb + cl * 64 + pk1);
        }

        #pragma unroll
        for (int ks = 0; ks < 2; ks++)
            #pragma unroll
            for (int rt = 0; rt < 2; rt++)
                #pragma unroll
                for (int ct = 0; ct < 2; ct++)
                    acc[rt][ct] = __builtin_amdgcn_mfma_f32_32x32x16_bf16(
                        af[rt][ks], bfr[ct][ks], acc[rt][ct], 0, 0, 0);

        if (ki == 7) {   // fold tile into running max; re-init acc with next bias
            #pragma unroll
            for (int ct = 0; ct < 2; ct++) {
                const unsigned code = (unsigned)(cg0 + ct8 * 256 + w * 64 + ct * 32 + l32);
                const float nb = (ct8 < 1) ? -hcv[1][ct] : 0.0f;
                #pragma unroll
                for (int rt = 0; rt < 2; rt++) {
                    #pragma unroll
                    for (int r = 0; r < 16; r++) {
                        unsigned u = (__float_as_uint(acc[rt][ct][r]) & 0xFFFFF800u) | code;
                        mp[rt][r] = fmaxf(mp[rt][r], __uint_as_float(u));
                        acc[rt][ct][r] = nb;
                    }
                }
            }
        }
        cur ^= 1;
    }

    // ---- cross-lane argmax over the 32 lanes sharing each row ----
    #pragma unroll
    for (int m = 1; m <= 16; m <<= 1)
        #pragma unroll
        for (int rt = 0; rt < 2; rt++)
            #pragma unroll
            for (int r = 0; r < 16; r++)
                mp[rt][r] = fmaxf(mp[rt][r], __shfl_xor(mp[rt][r], m, 64));

    if (l32 == 0) {
        #pragma unroll
        for (int rt = 0; rt < 2; rt++)
            #pragma unroll
            for (int r = 0; r < 16; r++) {
                const int row = rt * 32 + (r & 3) + 8 * (r >> 2) + 4 * h;
                red[row][w] = mp[rt][r];
            }
    }
    __syncthreads();
    if (t < 64) {
        float b0 = fmaxf(fmaxf(red[t][0], red[t][1]), fmaxf(red[t][2], red[t][3]));
        part[(size_t)(row0 + t) * 4 + blockIdx.y] = b0;
    }
}

// ---------------- epilogue: reduce partials + gather + loss ---------------------
__global__ void finish_kernel(const float* __restrict__ x, const float* __restrict__ cb,
                              const float* __restrict__ part, float* __restrict__ out,
                              float* __restrict__ loss) {
    const int t = threadIdx.x;    // 256 threads cover D
    float lsum = 0.0f;
    #pragma unroll
    for (int r = 0; r < 16; r++) {
        const int row = blockIdx.x * 16 + r;
        float4 p = *(const float4*)&part[(size_t)row * 4];
        float b = fmaxf(fmaxf(p.x, p.y), fmaxf(p.z, p.w));
        const int code = (int)(__float_as_uint(b) & 2047u);
        const float c  = cb[(size_t)code * DIM + t];
        const float xv = x[(size_t)row * DIM + t];
        out[(size_t)row * DIM + t] = c;
        const float diff = xv - c;
        lsum += diff * diff;
    }
    #pragma unroll
    for (int o = 32; o > 0; o >>= 1) lsum += __shfl_down(lsum, o, 64);
    __shared__ float red[4];
    if ((t & 63) == 0) red[t >> 6] = lsum;
    __syncthreads();
    if (t == 0) {
        const float scale = 1.25f / (float)((size_t)N_ROWS * DIM);  // (beta+1)/(N*D)
        atomicAdd(loss, (red[0] + red[1] + red[2] + red[3]) * scale);
    }
}

extern "C" void kernel_launch(void* const* d_in, const int* in_sizes, int n_in,
                              void* d_out, int out_size, void* d_ws, size_t ws_size,
                              hipStream_t stream) {
    const float* x  = (const float*)d_in[0];
    const float* cb = (const float*)d_in[1];
    float* out  = (float*)d_out;
    float* loss = out + (size_t)N_ROWS * DIM;

    char* ws = (char*)d_ws;
    ushort_t* cbb    = (ushort_t*)ws;                               // 1 MB
    float*    halfcn = (float*)(ws + (size_t)KCODES * DIM * 2);     // 8 KB
    float*    part   = (float*)(ws + (size_t)KCODES * DIM * 2 + KCODES * 4);  // 512 KB

    prep_cb<<<KCODES, 256, 0, stream>>>(cb, cbb, halfcn, loss);
    argmin_mfma<<<dim3(N_ROWS / 64, 4), 256, 0, stream>>>(x, cbb, halfcn, part);
    finish_kernel<<<N_ROWS / 16, 256, 0, stream>>>(x, cb, part, out, loss);
}